// Round 1
// baseline (403.011 us; speedup 1.0000x reference)
//
#include <hip/hip_runtime.h>
#include <hip/hip_bf16.h>

// ---------------------------------------------------------------------------
// MultiLevelFeatureSampler: gather 83-tap multi-scale patches (7x7+5x5+3x3)
// around 2048 points over 128 channels, then FC 83 -> 256 via bf16 MFMA.
//
// R4 changes vs R3 (theory: sampler ~160us, floor ~55us; HBM/cache-bound):
//  - ONE block per point (512 thr, 8 waves): tap offsets computed once (was
//    2x), packed-W L2 traffic halved (2048 x 48KB, was 4096 x), block count
//    halved. Gather stays 21 items/thread (128*84/512).
//  - MFMA operands SWAPPED (A=W, B=patch): D row = output, D col = channel.
//    Each lane now holds 4 CONSECUTIVE outputs -> 16x global_store_dwordx4
//    instead of 64x scalar dword stores (same 64B-contiguous coalescing:
//    lanes {l, l+16, l+32, l+48} cover one channel's 64B chunk).
//  - Output stores are NONTEMPORAL: out (268MB) is write-once; regular
//    stores were streaming it through L2/L3 and evicting the 76MB feature
//    set, turning line-granular gather re-reads (~334MB of 64B lines) into
//    HBM misses. NT stores keep features L3-resident.
// ---------------------------------------------------------------------------

typedef __bf16 bf16x8 __attribute__((ext_vector_type(8)));
typedef float f32x4 __attribute__((ext_vector_type(4)));

#define C_TOT 128
#define NPTS  512
#define OUTD  256
#define DTOT  83     // 49 + 25 + 9
#define DPAD  84     // pad so 128*84 = 512*21 items exactly
#define KPAD  96     // 3 k-steps of 32
#define PITCH 104    // LDS row pitch in bf16: 208 B -> 16B-aligned rows
#define ITEMS 21     // gather items per thread (128*84/512)

// feat dims
#define H0 93
#define W0 305
#define H1 47
#define W1 153
#define H2 24
#define W2 77
#define STRIDE0 (H0*W0)
#define STRIDE1 (H1*W1)
#define STRIDE2 (H2*W2)

// ---------------------------------------------------------------------------
// Pack W (256 x 83 fp32) into bf16 MFMA fragments:
// Wb[((s*16 + nt)*64 + lane)*8 + j] = W[n][k],
//   n = nt*16 + (lane&15), k = s*32 + (lane>>4)*8 + j, zero for k >= 83.
// Used as the A operand now (m = output index); lane->element mapping of A
// and B fragments is identical on gfx950 16x16x32, so the pack is unchanged.
// ---------------------------------------------------------------------------
__global__ void pack_w_kernel(const float* __restrict__ W, __bf16* __restrict__ Wb) {
    int t = blockIdx.x * 256 + threadIdx.x;
    if (t >= 3 * 16 * 64) return;
    int lane = t & 63;
    int nt   = (t >> 6) & 15;
    int s    = t >> 10;
    int n    = nt * 16 + (lane & 15);
    int kbase = s * 32 + (lane >> 4) * 8;
    #pragma unroll
    for (int j = 0; j < 8; ++j) {
        int k = kbase + j;
        float v = (k < DTOT) ? W[n * DTOT + k] : 0.f;
        Wb[(size_t)t * 8 + j] = (__bf16)v;
    }
}

// ---------------------------------------------------------------------------
// Main fused kernel. Grid: (512 points, 4 batches), block 512 (8 waves).
// ---------------------------------------------------------------------------
__global__ __launch_bounds__(512, 4) void sampler_kernel(
    const float* __restrict__ points,
    const float* __restrict__ f0,
    const float* __restrict__ f1,
    const float* __restrict__ f2,
    const __bf16* __restrict__ Wb,
    const float* __restrict__ bias,
    float* __restrict__ out) {

    __shared__ __align__(16) __bf16 a_lds[C_TOT * PITCH];
    __shared__ unsigned s_off[DPAD];   // byte offset of tap d at channel 0
                                       // within its level's buffer

    const int tid = threadIdx.x;
    const int p   = blockIdx.x;
    const int b   = blockIdx.y;

    // ---- phase 1: 84 tap byte-offsets (tap 83 = dummy -> f2[c*stride2]) ----
    if (tid < DPAD) {
        if (tid == DTOT) {
            s_off[tid] = 0u;
        } else {
            int d = tid, l, dd, ks;
            if (d < 49)      { l = 0; dd = d;      ks = 7; }
            else if (d < 74) { l = 1; dd = d - 49; ks = 5; }
            else             { l = 2; dd = d - 74; ks = 3; }
            const int Hs[3] = {H0, H1, H2};
            const int Ws[3] = {W0, W1, W2};
            int H  = Hs[l];
            int Wd = Ws[l];
            int jj = dd / ks - ks / 2;   // row offset (outer)
            int kk = dd % ks - ks / 2;   // col offset (inner)
            float px = points[((size_t)(b * NPTS) + p) * 2 + 0];
            float py = points[((size_t)(b * NPTS) + p) * 2 + 1];
            float x = fminf(fmaxf(px * (float)(Wd - 1), 0.f), (float)(Wd - 1));
            float y = fminf(fmaxf(py * (float)(H  - 1), 0.f), (float)(H  - 1));
            float oxf = fminf(fmaxf(x + (float)kk, 0.f), (float)(Wd - 1));
            float oyf = fminf(fmaxf(y + (float)jj, 0.f), (float)(H  - 1));
            int ox = (int)oxf;           // floor == trunc (non-negative)
            int oy = (int)oyf;
            int stride = (l == 0) ? STRIDE0 : (l == 1) ? STRIDE1 : STRIDE2;
            // byte offset: (b*128)*stride*4 <= ~44MB; + c*stride*4 + intra
            // stays < 59MB -> u32 safe
            s_off[tid] = 4u * (unsigned)((b * C_TOT) * stride + oy * Wd + ox);
        }
    }
    // zero K-pad cols 84..95 (must be finite: NaN*0 = NaN in MFMA)
    for (int i = tid; i < C_TOT * (KPAD - DPAD); i += 512) {
        int r  = i / (KPAD - DPAD);
        int cc = DPAD + (i - r * (KPAD - DPAD));
        a_lds[r * PITCH + cc] = (__bf16)0.f;
    }
    __syncthreads();

    // ---- phase 2: gather, addr-compute fused with load (21 in flight) ----
    float v[ITEMS];
    #pragma unroll
    for (int k = 0; k < ITEMS; ++k) {
        int idx = tid + k * 512;          // < 10752
        int c = idx / DPAD;               // 0..127
        int d = idx - c * DPAD;           // 0..83
        unsigned off = s_off[d];
        bool ge1 = d >= 49, ge2 = d >= 74;
        unsigned strideb = ge2 ? 4u * STRIDE2 : (ge1 ? 4u * STRIDE1 : 4u * STRIDE0);
        const char* base = ge2 ? (const char*)f2 : (ge1 ? (const char*)f1
                                                        : (const char*)f0);
        v[k] = *(const float*)(base + (off + (unsigned)c * strideb));
    }
    #pragma unroll
    for (int k = 0; k < ITEMS; ++k) {
        int idx = tid + k * 512;
        int c = idx / DPAD;
        int d = idx - c * DPAD;
        a_lds[c * PITCH + d] = (__bf16)v[k];
    }
    __syncthreads();

    // ---- phase 3: 8 waves x (16 channels x 256 outputs), two N-passes ----
    const int wave = tid >> 6;
    const int lane = tid & 63;
    const int quad = lane >> 4;
    const int lrow = lane & 15;

    bf16x8 af[3];
    #pragma unroll
    for (int s = 0; s < 3; ++s)
        af[s] = *reinterpret_cast<const bf16x8*>(
            &a_lds[(wave * 16 + lrow) * PITCH + s * 32 + quad * 8]);

    // lane holds: channel = wave*16 + lrow (D col), outputs nt*16+quad*4+r
    // (D rows) -> 4 consecutive floats -> dwordx4 stores.
    size_t rowBase =
        (((size_t)(b * NPTS + p) * C_TOT) + wave * 16 + lrow) * OUTD + quad * 4;

    #pragma unroll
    for (int np = 0; np < 2; ++np) {
        f32x4 acc[8] = {};
        #pragma unroll
        for (int s = 0; s < 3; ++s) {
            const bf16x8* bptr =
                reinterpret_cast<const bf16x8*>(Wb) + ((s * 16 + np * 8) * 64 + lane);
            #pragma unroll
            for (int t = 0; t < 8; ++t)
                acc[t] = __builtin_amdgcn_mfma_f32_16x16x32_bf16(bptr[t * 64], af[s],
                                                                 acc[t], 0, 0, 0);
        }
        #pragma unroll
        for (int t = 0; t < 8; ++t) {
            int nt = np * 8 + t;
            f32x4 bv = *reinterpret_cast<const f32x4*>(&bias[nt * 16 + quad * 4]);
            f32x4 o = acc[t] + bv;
            __builtin_nontemporal_store(
                o, reinterpret_cast<f32x4*>(out + rowBase + (size_t)nt * 16));
        }
    }
}

extern "C" void kernel_launch(void* const* d_in, const int* in_sizes, int n_in,
                              void* d_out, int out_size, void* d_ws, size_t ws_size,
                              hipStream_t stream) {
    const float* points = (const float*)d_in[0];
    const float* f0     = (const float*)d_in[1];
    const float* f1     = (const float*)d_in[2];
    const float* f2     = (const float*)d_in[3];
    const float* W      = (const float*)d_in[4];
    const float* bias   = (const float*)d_in[5];
    float* out = (float*)d_out;
    __bf16* Wb = (__bf16*)d_ws;   // 48 KB scratch

    pack_w_kernel<<<dim3(12), dim3(256), 0, stream>>>(W, Wb);
    sampler_kernel<<<dim3(NPTS, 4), dim3(512), 0, stream>>>(
        points, f0, f1, f2, Wb, bias, out);
}

// Round 2
// 392.595 us; speedup vs baseline: 1.0265x; 1.0265x over previous
//
#include <hip/hip_runtime.h>
#include <hip/hip_bf16.h>

// ---------------------------------------------------------------------------
// MultiLevelFeatureSampler: gather 83-tap multi-scale patches (7x7+5x5+3x3)
// around 2048 points over 128 channels, then FC 83 -> 256 via bf16 MFMA.
//
// R5 = R4 minus nontemporal stores (the R4 regression).
// Evidence: R4 fills got ~5us faster each while total got ~20us slower ->
// NT stores moved the 268MB output drain out of the (overlap-friendly)
// harness fill and into the sampler, serializing it against the gather.
// Regular write-back stores retire at L2/L3; the poison fill pays the drain.
// Kept from R4:
//  - ONE block per point (512 thr, 8 waves): tap offsets computed once,
//    packed-W L2 traffic halved, block count halved.
//  - MFMA operands swapped (A=W, B=patch): lane holds 4 consecutive
//    outputs -> 16x global_store_dwordx4 instead of 64x scalar stores.
// ---------------------------------------------------------------------------

typedef __bf16 bf16x8 __attribute__((ext_vector_type(8)));
typedef float f32x4 __attribute__((ext_vector_type(4)));

#define C_TOT 128
#define NPTS  512
#define OUTD  256
#define DTOT  83     // 49 + 25 + 9
#define DPAD  84     // pad so 128*84 = 512*21 items exactly
#define KPAD  96     // 3 k-steps of 32
#define PITCH 104    // LDS row pitch in bf16: 208 B -> 16B-aligned rows
#define ITEMS 21     // gather items per thread (128*84/512)

// feat dims
#define H0 93
#define W0 305
#define H1 47
#define W1 153
#define H2 24
#define W2 77
#define STRIDE0 (H0*W0)
#define STRIDE1 (H1*W1)
#define STRIDE2 (H2*W2)

// ---------------------------------------------------------------------------
// Pack W (256 x 83 fp32) into bf16 MFMA fragments:
// Wb[((s*16 + nt)*64 + lane)*8 + j] = W[n][k],
//   n = nt*16 + (lane&15), k = s*32 + (lane>>4)*8 + j, zero for k >= 83.
// Used as the A operand (m = output index); lane->element mapping of A and
// B fragments is identical on gfx950 16x16x32, so the pack is unchanged.
// ---------------------------------------------------------------------------
__global__ void pack_w_kernel(const float* __restrict__ W, __bf16* __restrict__ Wb) {
    int t = blockIdx.x * 256 + threadIdx.x;
    if (t >= 3 * 16 * 64) return;
    int lane = t & 63;
    int nt   = (t >> 6) & 15;
    int s    = t >> 10;
    int n    = nt * 16 + (lane & 15);
    int kbase = s * 32 + (lane >> 4) * 8;
    #pragma unroll
    for (int j = 0; j < 8; ++j) {
        int k = kbase + j;
        float v = (k < DTOT) ? W[n * DTOT + k] : 0.f;
        Wb[(size_t)t * 8 + j] = (__bf16)v;
    }
}

// ---------------------------------------------------------------------------
// Main fused kernel. Grid: (512 points, 4 batches), block 512 (8 waves).
// ---------------------------------------------------------------------------
__global__ __launch_bounds__(512, 4) void sampler_kernel(
    const float* __restrict__ points,
    const float* __restrict__ f0,
    const float* __restrict__ f1,
    const float* __restrict__ f2,
    const __bf16* __restrict__ Wb,
    const float* __restrict__ bias,
    float* __restrict__ out) {

    __shared__ __align__(16) __bf16 a_lds[C_TOT * PITCH];
    __shared__ unsigned s_off[DPAD];   // byte offset of tap d at channel 0
                                       // within its level's buffer

    const int tid = threadIdx.x;
    const int p   = blockIdx.x;
    const int b   = blockIdx.y;

    // ---- phase 1: 84 tap byte-offsets (tap 83 = dummy -> f2[c*stride2]) ----
    if (tid < DPAD) {
        if (tid == DTOT) {
            s_off[tid] = 0u;
        } else {
            int d = tid, l, dd, ks;
            if (d < 49)      { l = 0; dd = d;      ks = 7; }
            else if (d < 74) { l = 1; dd = d - 49; ks = 5; }
            else             { l = 2; dd = d - 74; ks = 3; }
            const int Hs[3] = {H0, H1, H2};
            const int Ws[3] = {W0, W1, W2};
            int H  = Hs[l];
            int Wd = Ws[l];
            int jj = dd / ks - ks / 2;   // row offset (outer)
            int kk = dd % ks - ks / 2;   // col offset (inner)
            float px = points[((size_t)(b * NPTS) + p) * 2 + 0];
            float py = points[((size_t)(b * NPTS) + p) * 2 + 1];
            float x = fminf(fmaxf(px * (float)(Wd - 1), 0.f), (float)(Wd - 1));
            float y = fminf(fmaxf(py * (float)(H  - 1), 0.f), (float)(H  - 1));
            float oxf = fminf(fmaxf(x + (float)kk, 0.f), (float)(Wd - 1));
            float oyf = fminf(fmaxf(y + (float)jj, 0.f), (float)(H  - 1));
            int ox = (int)oxf;           // floor == trunc (non-negative)
            int oy = (int)oyf;
            int stride = (l == 0) ? STRIDE0 : (l == 1) ? STRIDE1 : STRIDE2;
            // byte offset: (b*128)*stride*4 + c*stride*4 + intra < 59MB
            // -> u32 safe
            s_off[tid] = 4u * (unsigned)((b * C_TOT) * stride + oy * Wd + ox);
        }
    }
    // zero K-pad cols 84..95 (must be finite: NaN*0 = NaN in MFMA)
    for (int i = tid; i < C_TOT * (KPAD - DPAD); i += 512) {
        int r  = i / (KPAD - DPAD);
        int cc = DPAD + (i - r * (KPAD - DPAD));
        a_lds[r * PITCH + cc] = (__bf16)0.f;
    }
    __syncthreads();

    // ---- phase 2: gather, addr-compute fused with load (21 in flight) ----
    float v[ITEMS];
    #pragma unroll
    for (int k = 0; k < ITEMS; ++k) {
        int idx = tid + k * 512;          // < 10752
        int c = idx / DPAD;               // 0..127
        int d = idx - c * DPAD;           // 0..83
        unsigned off = s_off[d];
        bool ge1 = d >= 49, ge2 = d >= 74;
        unsigned strideb = ge2 ? 4u * STRIDE2 : (ge1 ? 4u * STRIDE1 : 4u * STRIDE0);
        const char* base = ge2 ? (const char*)f2 : (ge1 ? (const char*)f1
                                                        : (const char*)f0);
        v[k] = *(const float*)(base + (off + (unsigned)c * strideb));
    }
    #pragma unroll
    for (int k = 0; k < ITEMS; ++k) {
        int idx = tid + k * 512;
        int c = idx / DPAD;
        int d = idx - c * DPAD;
        a_lds[c * PITCH + d] = (__bf16)v[k];
    }
    __syncthreads();

    // ---- phase 3: 8 waves x (16 channels x 256 outputs), two N-passes ----
    const int wave = tid >> 6;
    const int lane = tid & 63;
    const int quad = lane >> 4;
    const int lrow = lane & 15;

    bf16x8 af[3];
    #pragma unroll
    for (int s = 0; s < 3; ++s)
        af[s] = *reinterpret_cast<const bf16x8*>(
            &a_lds[(wave * 16 + lrow) * PITCH + s * 32 + quad * 8]);

    // lane holds: channel = wave*16 + lrow (D col), outputs nt*16+quad*4+r
    // (D rows) -> 4 consecutive floats -> dwordx4 stores.
    size_t rowBase =
        (((size_t)(b * NPTS + p) * C_TOT) + wave * 16 + lrow) * OUTD + quad * 4;

    #pragma unroll
    for (int np = 0; np < 2; ++np) {
        f32x4 acc[8] = {};
        #pragma unroll
        for (int s = 0; s < 3; ++s) {
            const bf16x8* bptr =
                reinterpret_cast<const bf16x8*>(Wb) + ((s * 16 + np * 8) * 64 + lane);
            #pragma unroll
            for (int t = 0; t < 8; ++t)
                acc[t] = __builtin_amdgcn_mfma_f32_16x16x32_bf16(bptr[t * 64], af[s],
                                                                 acc[t], 0, 0, 0);
        }
        #pragma unroll
        for (int t = 0; t < 8; ++t) {
            int nt = np * 8 + t;
            f32x4 bv = *reinterpret_cast<const f32x4*>(&bias[nt * 16 + quad * 4]);
            f32x4 o = acc[t] + bv;
            *reinterpret_cast<f32x4*>(out + rowBase + (size_t)nt * 16) = o;
        }
    }
}

extern "C" void kernel_launch(void* const* d_in, const int* in_sizes, int n_in,
                              void* d_out, int out_size, void* d_ws, size_t ws_size,
                              hipStream_t stream) {
    const float* points = (const float*)d_in[0];
    const float* f0     = (const float*)d_in[1];
    const float* f1     = (const float*)d_in[2];
    const float* f2     = (const float*)d_in[3];
    const float* W      = (const float*)d_in[4];
    const float* bias   = (const float*)d_in[5];
    float* out = (float*)d_out;
    __bf16* Wb = (__bf16*)d_ws;   // 48 KB scratch

    pack_w_kernel<<<dim3(12), dim3(256), 0, stream>>>(W, Wb);
    sampler_kernel<<<dim3(NPTS, 4), dim3(512), 0, stream>>>(
        points, f0, f1, f2, Wb, bias, out);
}

// Round 3
// 382.064 us; speedup vs baseline: 1.0548x; 1.0276x over previous
//
#include <hip/hip_runtime.h>
#include <hip/hip_bf16.h>

// ---------------------------------------------------------------------------
// MultiLevelFeatureSampler: gather 83-tap multi-scale patches (7x7+5x5+3x3)
// around 2048 points over 128 channels, then FC 83 -> 256 via bf16 MFMA.
// R6 = verbatim revert to the R3 kernel (best measured: 383.0us).
// Session findings (R4/R5):
//  - NT output stores: -20us regression (forces 268MB drain inside the
//    sampler instead of letting L2 write-back overlap the harness fill).
//  - merged 512-thr block + swapped-MFMA dwordx4 stores: -15us regression
//    vs this structure (store-pattern/occupancy interaction; fills in that
//    session were FASTER, so the delta is the sampler itself).
//  - This kernel's sampler ~45us = its 268MB-output write-BW floor; the
//    remaining ~340us of the timed region is two harness 1GiB poison
//    fills at ~80% HBM peak. Total structural floor ~380-385us.
// ---------------------------------------------------------------------------

typedef __bf16 bf16x8 __attribute__((ext_vector_type(8)));
typedef float f32x4 __attribute__((ext_vector_type(4)));

#define C_TOT 128
#define NPTS  512
#define OUTD  256
#define DTOT  83     // 49 + 25 + 9
#define DPAD  84     // pad so 64*84 = 256*21 items exactly
#define KPAD  96     // 3 k-steps of 32
#define PITCH 104    // LDS row pitch in bf16: 208 B -> 16B-aligned rows
#define ITEMS 21     // gather items per thread

// feat dims
#define H0 93
#define W0 305
#define H1 47
#define W1 153
#define H2 24
#define W2 77
#define STRIDE0 (H0*W0)
#define STRIDE1 (H1*W1)
#define STRIDE2 (H2*W2)

// ---------------------------------------------------------------------------
// Pack W (256 x 83 fp32) into bf16 MFMA-B fragments:
// Wb[((s*16 + nt)*64 + lane)*8 + j] = W[n][k],
//   n = nt*16 + (lane&15), k = s*32 + (lane>>4)*8 + j, zero for k >= 83.
// ---------------------------------------------------------------------------
__global__ void pack_w_kernel(const float* __restrict__ W, __bf16* __restrict__ Wb) {
    int t = blockIdx.x * 256 + threadIdx.x;
    if (t >= 3 * 16 * 64) return;
    int lane = t & 63;
    int nt   = (t >> 6) & 15;
    int s    = t >> 10;
    int n    = nt * 16 + (lane & 15);
    int kbase = s * 32 + (lane >> 4) * 8;
    #pragma unroll
    for (int j = 0; j < 8; ++j) {
        int k = kbase + j;
        float v = (k < DTOT) ? W[n * DTOT + k] : 0.f;
        Wb[(size_t)t * 8 + j] = (__bf16)v;
    }
}

// ---------------------------------------------------------------------------
// Main fused kernel. Grid: (2 halves, 512 points, 4 batches), block 256.
// ---------------------------------------------------------------------------
__global__ __launch_bounds__(256, 4) void sampler_kernel(
    const float* __restrict__ points,
    const float* __restrict__ f0,
    const float* __restrict__ f1,
    const float* __restrict__ f2,
    const __bf16* __restrict__ Wb,
    const float* __restrict__ bias,
    float* __restrict__ out) {

    __shared__ __align__(16) __bf16 a_lds[64 * PITCH];
    __shared__ unsigned s_off[DPAD];   // byte offset of tap d at channel c0
                                       // within its level's buffer

    const int tid  = threadIdx.x;
    const int half = blockIdx.x;
    const int p    = blockIdx.y;
    const int b    = blockIdx.z;
    const int c0   = half * 64;

    // ---- phase 1: 84 tap byte-offsets (tap 83 = dummy -> f2[ c*stride2 ]) ----
    if (tid < DPAD) {
        if (tid == DTOT) {
            s_off[tid] = 0u;
        } else {
            int d = tid, l, dd, ks;
            if (d < 49)      { l = 0; dd = d;      ks = 7; }
            else if (d < 74) { l = 1; dd = d - 49; ks = 5; }
            else             { l = 2; dd = d - 74; ks = 3; }
            const int Hs[3] = {H0, H1, H2};
            const int Ws[3] = {W0, W1, W2};
            int H  = Hs[l];
            int Wd = Ws[l];
            int jj = dd / ks - ks / 2;   // row offset (outer)
            int kk = dd % ks - ks / 2;   // col offset (inner)
            float px = points[((size_t)(b * NPTS) + p) * 2 + 0];
            float py = points[((size_t)(b * NPTS) + p) * 2 + 1];
            float x = fminf(fmaxf(px * (float)(Wd - 1), 0.f), (float)(Wd - 1));
            float y = fminf(fmaxf(py * (float)(H  - 1), 0.f), (float)(H  - 1));
            float oxf = fminf(fmaxf(x + (float)kk, 0.f), (float)(Wd - 1));
            float oyf = fminf(fmaxf(y + (float)jj, 0.f), (float)(H  - 1));
            int ox = (int)oxf;           // floor == trunc (non-negative)
            int oy = (int)oyf;
            int stride = (l == 0) ? STRIDE0 : (l == 1) ? STRIDE1 : STRIDE2;
            // max elem index ~14.5M < 2^24; byte offset < 2^26 -> u32 safe
            s_off[tid] = 4u * (unsigned)((b * C_TOT + c0) * stride + oy * Wd + ox);
        }
    }
    // zero K-pad cols 84..95 (must be finite: NaN*0 = NaN in MFMA)
    for (int i = tid; i < 64 * (KPAD - DPAD); i += 256) {
        int r  = i / (KPAD - DPAD);
        int cc = DPAD + (i - r * (KPAD - DPAD));
        a_lds[r * PITCH + cc] = (__bf16)0.f;
    }
    __syncthreads();

    // ---- phase 2: gather, addr-compute fused with load (21 in flight) ----
    float v[ITEMS];
    #pragma unroll
    for (int k = 0; k < ITEMS; ++k) {
        int idx = tid + k * 256;          // < 5376
        int c = idx / DPAD;               // 0..63
        int d = idx - c * DPAD;           // 0..83
        unsigned off = s_off[d];
        bool ge1 = d >= 49, ge2 = d >= 74;
        unsigned strideb = ge2 ? 4u * STRIDE2 : (ge1 ? 4u * STRIDE1 : 4u * STRIDE0);
        const char* base = ge2 ? (const char*)f2 : (ge1 ? (const char*)f1
                                                        : (const char*)f0);
        v[k] = *(const float*)(base + (off + (unsigned)c * strideb));
    }
    #pragma unroll
    for (int k = 0; k < ITEMS; ++k) {
        int idx = tid + k * 256;
        int c = idx / DPAD;
        int d = idx - c * DPAD;
        a_lds[c * PITCH + d] = (__bf16)v[k];
    }
    __syncthreads();

    // ---- phase 3: 4 waves x (16 rows x 256 cols), two N-passes of 8 ----
    const int wave = tid >> 6;
    const int lane = tid & 63;
    const int quad = lane >> 4;
    const int lrow = lane & 15;

    bf16x8 af[3];
    #pragma unroll
    for (int s = 0; s < 3; ++s)
        af[s] = *reinterpret_cast<const bf16x8*>(
            &a_lds[(wave * 16 + lrow) * PITCH + s * 32 + quad * 8]);

    size_t rowBase =
        (((size_t)(b * NPTS + p) * C_TOT) + c0 + wave * 16 + quad * 4) * OUTD + lrow;

    #pragma unroll
    for (int np = 0; np < 2; ++np) {
        f32x4 acc[8] = {};
        #pragma unroll
        for (int s = 0; s < 3; ++s) {
            const bf16x8* bptr =
                reinterpret_cast<const bf16x8*>(Wb) + ((s * 16 + np * 8) * 64 + lane);
            #pragma unroll
            for (int t = 0; t < 8; ++t)
                acc[t] = __builtin_amdgcn_mfma_f32_16x16x32_bf16(af[s], bptr[t * 64],
                                                                 acc[t], 0, 0, 0);
        }
        #pragma unroll
        for (int t = 0; t < 8; ++t) {
            int nt = np * 8 + t;
            float bv = bias[nt * 16 + lrow];
            #pragma unroll
            for (int r = 0; r < 4; ++r)
                out[rowBase + (size_t)r * OUTD + nt * 16] = acc[t][r] + bv;
        }
    }
}

extern "C" void kernel_launch(void* const* d_in, const int* in_sizes, int n_in,
                              void* d_out, int out_size, void* d_ws, size_t ws_size,
                              hipStream_t stream) {
    const float* points = (const float*)d_in[0];
    const float* f0     = (const float*)d_in[1];
    const float* f1     = (const float*)d_in[2];
    const float* f2     = (const float*)d_in[3];
    const float* W      = (const float*)d_in[4];
    const float* bias   = (const float*)d_in[5];
    float* out = (float*)d_out;
    __bf16* Wb = (__bf16*)d_ws;   // 48 KB scratch

    pack_w_kernel<<<dim3(12), dim3(256), 0, stream>>>(W, Wb);
    sampler_kernel<<<dim3(2, NPTS, 4), dim3(256), 0, stream>>>(
        points, f0, f1, f2, Wb, bias, out);
}